// Round 8
// baseline (490.538 us; speedup 1.0000x reference)
//
#include <hip/hip_runtime.h>
#include <stdint.h>

constexpr int C = 128;
constexpr int F1 = 192;  // C + HID

// ---------------- edge dtype detection ----------------
__global__ void k_detect(const int* __restrict__ ei, int E, int* __restrict__ res) {
    int t = blockIdx.x * 256 + threadIdx.x;
    int idx = 2 * t + 1;                 // odd word; t < 4096 <= E so in bounds
    if (idx < 2 * E && ei[idx] != 0) atomicOr(&res[5], 1);
}

// ---------------- degree ----------------
__global__ void k_deg(const int* __restrict__ ei, int E, const int* __restrict__ res,
                      int* __restrict__ outdeg, int* __restrict__ indeg) {
    int e = blockIdx.x * 256 + threadIdx.x;
    if (e < E) {
        bool i64 = (res[5] == 0);
        int s = i64 ? ei[2 * e]       : ei[e];
        int d = i64 ? ei[2 * (E + e)] : ei[E + e];
        atomicAdd(&outdeg[s], 1);
        atomicAdd(&indeg[d], 1);
    }
}

// ---------------- scan stage 1 (block-local excl. scan + block sums), fused norm ----------------
__global__ void scan1(const int* __restrict__ in, int* __restrict__ out,
                      int* __restrict__ bsums, int n,
                      const int* __restrict__ outdeg, float* __restrict__ nsrc,
                      float* __restrict__ ndst) {
    __shared__ int sh[1024];
    int i = blockIdx.x * 1024 + threadIdx.x;
    int v = (i < n) ? in[i] : 0;
    if (nsrc && i < n) {
        int od = outdeg[i]; if (od < 1) od = 1;
        int id = v;         if (id < 1) id = 1;
        nsrc[i] = (float)(1.0 / sqrt((double)od));
        ndst[i] = (float)(1.0 / sqrt((double)id));
    }
    sh[threadIdx.x] = v;
    __syncthreads();
    for (int off = 1; off < 1024; off <<= 1) {
        int t = (threadIdx.x >= off) ? sh[threadIdx.x - off] : 0;
        __syncthreads();
        sh[threadIdx.x] += t;
        __syncthreads();
    }
    if (i < n) out[i] = sh[threadIdx.x] - v;   // exclusive
    if (threadIdx.x == 1023) bsums[blockIdx.x] = sh[1023];
}

// ---------------- scan stage 2: add prefix of raw bsums (computed in-block), optional copy ----------------
__global__ void scan3b(int* __restrict__ data, const int* __restrict__ bsums,
                       int* __restrict__ copy2, int n) {
    __shared__ int sh[1024];
    int t = threadIdx.x;
    sh[t] = (t < (int)blockIdx.x) ? bsums[t] : 0;   // gridDim <= 1024
    __syncthreads();
    for (int off = 512; off > 0; off >>= 1) {
        if (t < off) sh[t] += sh[t + off];
        __syncthreads();
    }
    int boff = sh[0];
    int i = blockIdx.x * 1024 + t;
    if (i < n) {
        int v = data[i] + boff;
        data[i] = v;
        if (copy2) copy2[i] = v;
    }
}

// ---------------- CSR build (by dst) ----------------
__global__ void k_csr(const int* __restrict__ ei, int E, const int* __restrict__ res,
                      int* __restrict__ cursor, int* __restrict__ csr) {
    int e = blockIdx.x * 256 + threadIdx.x;
    if (e < E) {
        bool i64 = (res[5] == 0);
        int s = i64 ? ei[2 * e]       : ei[e];
        int d = i64 ? ei[2 * (E + e)] : ei[E + e];
        int p = atomicAdd(&cursor[d], 1);
        csr[p] = s;
    }
}

// ---------------- layer-1 aggregation: one wave per node ----------------
// Sorted in-wave neighbor list (deterministic summation order across replays).
// Gather loop unroll-4: 4 x 512B row loads in flight (latency-in-flight bound).
__global__ __launch_bounds__(256) void k_agg(const float* __restrict__ x,
        int* __restrict__ csr, const int* __restrict__ indeg,
        const int* __restrict__ offsets, const float* __restrict__ nsrc,
        const float* __restrict__ ndst, float* __restrict__ g, int N) {
    int wid  = (blockIdx.x * 256 + threadIdx.x) >> 6;  // node id (wave-uniform)
    int lane = threadIdx.x & 63;
    if (wid >= N) return;
    int deg = indeg[wid];
    int off = offsets[wid];
    float acc0 = 0.f, acc1 = 0.f;
    if (deg > 0 && deg <= 64) {
        int v = (lane < deg) ? csr[off + lane] : 0x7fffffff;
        int rank = 0;
        for (int j = 0; j < deg; ++j) {
            int vj = __builtin_amdgcn_readlane(v, j);
            rank += (vj < v) || (vj == v && j < lane);
        }
        int sv = __builtin_amdgcn_ds_permute(rank << 2, v);
        if (lane < deg) csr[off + lane] = sv;                // sorted write-back for k_l2
        float nsv = (lane < deg) ? nsrc[sv] : 0.f;
        int nsb = __float_as_int(nsv);
        int i = 0;
        for (; i + 3 < deg; i += 4) {
            int   s0 = __builtin_amdgcn_readlane(sv, i);
            int   s1 = __builtin_amdgcn_readlane(sv, i + 1);
            int   s2 = __builtin_amdgcn_readlane(sv, i + 2);
            int   s3 = __builtin_amdgcn_readlane(sv, i + 3);
            float n0 = __int_as_float(__builtin_amdgcn_readlane(nsb, i));
            float n1 = __int_as_float(__builtin_amdgcn_readlane(nsb, i + 1));
            float n2 = __int_as_float(__builtin_amdgcn_readlane(nsb, i + 2));
            float n3 = __int_as_float(__builtin_amdgcn_readlane(nsb, i + 3));
            float2 x0 = ((const float2*)x)[(size_t)s0 * 64 + lane];
            float2 x1 = ((const float2*)x)[(size_t)s1 * 64 + lane];
            float2 x2 = ((const float2*)x)[(size_t)s2 * 64 + lane];
            float2 x3 = ((const float2*)x)[(size_t)s3 * 64 + lane];
            acc0 = fmaf(x0.x, n0, acc0); acc1 = fmaf(x0.y, n0, acc1);
            acc0 = fmaf(x1.x, n1, acc0); acc1 = fmaf(x1.y, n1, acc1);
            acc0 = fmaf(x2.x, n2, acc0); acc1 = fmaf(x2.y, n2, acc1);
            acc0 = fmaf(x3.x, n3, acc0); acc1 = fmaf(x3.y, n3, acc1);
        }
        for (; i < deg; ++i) {
            int   s0 = __builtin_amdgcn_readlane(sv, i);
            float n0 = __int_as_float(__builtin_amdgcn_readlane(nsb, i));
            float2 x0 = ((const float2*)x)[(size_t)s0 * 64 + lane];
            acc0 = fmaf(x0.x, n0, acc0); acc1 = fmaf(x0.y, n0, acc1);
        }
    } else if (deg > 64) {
        for (int i = 0; i < deg; ++i) {
            int s = csr[off + i];
            float ns = nsrc[s];
            float2 xr = ((const float2*)x)[(size_t)s * 64 + lane];
            acc0 = fmaf(xr.x, ns, acc0);
            acc1 = fmaf(xr.y, ns, acc1);
        }
    }
    float nd = ndst[wid];
    ((float2*)g)[(size_t)wid * 64 + lane] = make_float2(acc0 * nd, acc1 * nd);
}

// ---------------- fused GEMM + ReLU + dot(W2): register-blocked LDS GEMM ----------------
// Block: 192 nodes x 192 j; 256 threads = 16 ng x 16 jg; thread tile 12x12 =
// 144 acc (all compile-time-indexed -> VGPR-resident). Per kk: 6 b128 LDS
// reads per 144 fma (round-7 was 5/96): LDS ~82k cyc/CU vs VALU ~74k -> near
// balance. At[32][196] pad, Wt[32][200] pad: compute reads are 16-lane
// broadcasts to <=2-way banks (free). LDS 50.7KB.
__global__ __launch_bounds__(256, 2) void k_gemm(const float* __restrict__ g,
        const float* __restrict__ W1, const float* __restrict__ b1,
        const float* __restrict__ W2, const float* __restrict__ nsrc,
        float* __restrict__ tn, int N) {
    __shared__ float At[32 * 196];   // 25.1 KB : At[k][node]
    __shared__ float Wt[32 * 200];   // 25.6 KB : Wt[k][j]
    int T  = threadIdx.x;
    int ng = T >> 4, jg = T & 15;
    int nb = blockIdx.x * 192;
    float acc[12][12];
    #pragma unroll
    for (int jj = 0; jj < 12; ++jj) {
        float b = b1[jg * 12 + jj];
        #pragma unroll
        for (int i = 0; i < 12; ++i) acc[i][jj] = b;
    }
    for (int s = 0; s < 4; ++s) {
        int k0 = s * 32;
        if (s) __syncthreads();          // previous step's reads done before overwrite
        // ---- stage A (transposed, pad-196) ----
        int kq = T & 7;
        #pragma unroll
        for (int t = 0; t < 6; ++t) {
            int nl = (T >> 3) + 32 * t;
            int node = nb + nl;
            float4 v = make_float4(0.f, 0.f, 0.f, 0.f);
            if (node < N) v = *(const float4*)(g + (size_t)node * 128 + k0 + kq * 4);
            int base = (kq * 4) * 196 + nl;
            At[base]       = v.x;
            At[base + 196] = v.y;
            At[base + 392] = v.z;
            At[base + 588] = v.w;
        }
        // ---- stage W (row-major, pad-200) ----
        #pragma unroll
        for (int i = 0; i < 6; ++i) {
            int idx = i * 256 + T;
            int r = idx / 48, j4 = idx - r * 48;
            float4 v = *(const float4*)(W1 + (k0 + r) * 192 + j4 * 4);
            *(float4*)&Wt[r * 200 + j4 * 4] = v;
        }
        __syncthreads();
        // ---- compute: 32 kk x (6 b128 reads, 144 fma) ----
        for (int kk = 0; kk < 32; ++kk) {
            float4 a0 = *(const float4*)&At[kk * 196 + ng * 12];
            float4 a1 = *(const float4*)&At[kk * 196 + ng * 12 + 4];
            float4 a2 = *(const float4*)&At[kk * 196 + ng * 12 + 8];
            float4 w0 = *(const float4*)&Wt[kk * 200 + jg * 12];
            float4 w1 = *(const float4*)&Wt[kk * 200 + jg * 12 + 4];
            float4 w2 = *(const float4*)&Wt[kk * 200 + jg * 12 + 8];
            float a[12] = {a0.x, a0.y, a0.z, a0.w, a1.x, a1.y, a1.z, a1.w,
                           a2.x, a2.y, a2.z, a2.w};
            float w[12] = {w0.x, w0.y, w0.z, w0.w, w1.x, w1.y, w1.z, w1.w,
                           w2.x, w2.y, w2.z, w2.w};
            #pragma unroll
            for (int i = 0; i < 12; ++i) {
                #pragma unroll
                for (int jj = 0; jj < 12; ++jj)
                    acc[i][jj] = fmaf(a[i], w[jj], acc[i][jj]);
            }
        }
    }
    // ---- epilogue: relu . W2, 16-lane butterfly per node, store tn ----
    float w2r[12];
    #pragma unroll
    for (int jj = 0; jj < 12; ++jj) w2r[jj] = W2[jg * 12 + jj];
    #pragma unroll
    for (int i = 0; i < 12; ++i) {
        float p = 0.f;
        #pragma unroll
        for (int jj = 0; jj < 12; ++jj) p = fmaf(fmaxf(acc[i][jj], 0.f), w2r[jj], p);
        p += __shfl_xor(p, 1);
        p += __shfl_xor(p, 2);
        p += __shfl_xor(p, 4);
        p += __shfl_xor(p, 8);
        if (jg == 0) {
            int node = nb + ng * 12 + i;
            if (node < N) tn[node] = p * nsrc[node];
        }
    }
}

// ---------------- layer-2 scalar aggregation + |score| bits + histogram ----------------
__global__ void k_l2(const int* __restrict__ csr, const int* __restrict__ indeg,
                     const int* __restrict__ offsets, const float* __restrict__ tn,
                     const float* __restrict__ ndst, const float* __restrict__ b2,
                     unsigned int* __restrict__ U, int* __restrict__ hist1, int N) {
    int n = blockIdx.x * 256 + threadIdx.x;
    if (n >= N) return;
    int deg = indeg[n], off = offsets[n];
    float s = 0.f;
    for (int i = 0; i < deg; ++i) s += tn[csr[off + i]];   // sorted order -> deterministic
    float sc = ndst[n] * s + b2[0];
    unsigned int u = __float_as_uint(fabsf(sc));
    U[n] = u;
    atomicAdd(&hist1[u >> 16], 1);
}

// ---------------- radix-select pass 1: high 16 bits ----------------
__global__ void k_findbin1(const int* __restrict__ hist, int k, int* __restrict__ res) {
    __shared__ int sh[1024];
    int t = threadIdx.x;
    int base = 65535 - 64 * t;
    int s = 0;
    for (int q = 0; q < 64; ++q) s += hist[base - q];
    sh[t] = s;
    __syncthreads();
    int v = s;
    for (int off = 1; off < 1024; off <<= 1) {
        int u = (t >= off) ? sh[t - off] : 0;
        __syncthreads();
        sh[t] += u;
        __syncthreads();
    }
    int before = sh[t] - v;
    if (before < k && sh[t] >= k) {
        int cum = before;
        for (int q = 0; q < 64; ++q) {
            int b = base - q;
            int hh = hist[b];
            if (cum + hh >= k) { res[0] = b; res[1] = k - cum; break; }
            cum += hh;
        }
    }
}

__global__ void k_hist2(const unsigned int* __restrict__ U, const int* __restrict__ res,
                        int* __restrict__ hist2, int N) {
    int n = blockIdx.x * 256 + threadIdx.x;
    if (n < N) {
        unsigned int u = U[n];
        if ((int)(u >> 16) == res[0]) atomicAdd(&hist2[u & 0xffff], 1);
    }
}

// ---------------- radix-select pass 2: low 16 bits ----------------
__global__ void k_findbin2(const int* __restrict__ hist, int* __restrict__ res) {
    __shared__ int sh[1024];
    int k = res[1];
    int t = threadIdx.x;
    int base = 65535 - 64 * t;
    int s = 0;
    for (int q = 0; q < 64; ++q) s += hist[base - q];
    sh[t] = s;
    __syncthreads();
    int v = s;
    for (int off = 1; off < 1024; off <<= 1) {
        int u = (t >= off) ? sh[t - off] : 0;
        __syncthreads();
        sh[t] += u;
        __syncthreads();
    }
    int before = sh[t] - v;
    if (before < k && sh[t] >= k) {
        int cum = before;
        for (int q = 0; q < 64; ++q) {
            int b = base - q;
            int hh = hist[b];
            if (cum + hh >= k) {
                res[2] = (int)(((unsigned int)res[0] << 16) | (unsigned int)b);  // threshold bits
                res[3] = k - cum;                                                // # ties to keep
                break;
            }
            cum += hh;
        }
    }
}

// ---------------- selection pair-scan: gt/eq packed block scan ----------------
// Replaces flags+ties+scan chain. gt counts in low 16, eq counts in high 16
// (block totals <= 1024 -> no cross-field carry).
__global__ void pscan1(const unsigned int* __restrict__ U, const int* __restrict__ res,
                       int* __restrict__ ppos, int* __restrict__ pbsums, int n) {
    __shared__ int sh[1024];
    unsigned int T = (unsigned int)res[2];
    int i = blockIdx.x * 1024 + threadIdx.x;
    int v = 0;
    if (i < n) {
        unsigned int u = U[i];
        v = (u > T) ? 1 : ((u == T) ? 0x10000 : 0);
    }
    sh[threadIdx.x] = v;
    __syncthreads();
    for (int off = 1; off < 1024; off <<= 1) {
        int t = (threadIdx.x >= off) ? sh[threadIdx.x - off] : 0;
        __syncthreads();
        sh[threadIdx.x] += t;
        __syncthreads();
    }
    if (i < n) ppos[i] = sh[threadIdx.x] - v;   // exclusive packed prefix
    if (threadIdx.x == 1023) pbsums[blockIdx.x] = sh[1023];
}

// Final sel/pos: node selected iff gt, or (eq and eq-rank < need). Position =
// prefix_gt + min(prefix_eq, need). Exactly reproduces jax top_k + sort(idx)
// (ties broken by ascending node index).
__global__ void pscan2out(const unsigned int* __restrict__ U, const int* __restrict__ res,
                          const int* __restrict__ ppos, const int* __restrict__ pbsums,
                          int* __restrict__ sel, int* __restrict__ pos, int n) {
    __shared__ int sg[1024], se[1024];
    int t = threadIdx.x;
    int b = (t < (int)blockIdx.x) ? pbsums[t] : 0;   // gridDim <= 1024
    sg[t] = b & 0xffff;
    se[t] = b >> 16;
    __syncthreads();
    for (int off = 512; off > 0; off >>= 1) {
        if (t < off) { sg[t] += sg[t + off]; se[t] += se[t + off]; }
        __syncthreads();
    }
    int i = blockIdx.x * 1024 + t;
    if (i < n) {
        unsigned int T = (unsigned int)res[2];
        int need = res[3];
        unsigned int u = U[i];
        int p = ppos[i];
        int Pgt = (p & 0xffff) + sg[0];
        int Peq = (p >> 16) + se[0];
        int gt = (u > T), eq = (u == T);
        sel[i] = gt | (eq & (Peq < need ? 1 : 0));
        pos[i] = Pgt + (Peq < need ? Peq : need);
    }
}

// ---------------- compact rows: one wave per node ----------------
__global__ __launch_bounds__(256) void k_out(const float* __restrict__ x,
        const int* __restrict__ sel, const int* __restrict__ pos,
        float* __restrict__ out, int N) {
    int wid  = (blockIdx.x * 256 + threadIdx.x) >> 6;
    int lane = threadIdx.x & 63;
    if (wid >= N) return;
    if (sel[wid]) {
        int p = pos[wid];
        ((float2*)out)[(size_t)p * 64 + lane] = ((const float2*)x)[(size_t)wid * 64 + lane];
    }
}

extern "C" void kernel_launch(void* const* d_in, const int* in_sizes, int n_in,
                              void* d_out, int out_size, void* d_ws, size_t ws_size,
                              hipStream_t stream) {
    const float* x  = (const float*)d_in[0];
    const int*   ei = (const int*)d_in[1];
    const float* W1 = (const float*)d_in[2];
    const float* b1 = (const float*)d_in[3];
    const float* W2 = (const float*)d_in[4];
    const float* b2 = (const float*)d_in[5];
    int N = in_sizes[0] / C;            // 100000
    int E = in_sizes[1] / 2;            // 800000
    int k = out_size / C;               // harness-derived k

    char* w = (char*)d_ws;
    size_t ofs = 0;
    auto alloc = [&](size_t bytes) -> char* {
        char* p = w + ofs;
        ofs += (bytes + 511) & ~(size_t)511;
        return p;
    };
    // zero-init region first (single contiguous memset)
    int*   outdeg  = (int*)alloc((size_t)N * 4);
    int*   indeg   = (int*)alloc((size_t)N * 4);
    int*   hist1   = (int*)alloc(65536 * 4);
    int*   hist2   = (int*)alloc(65536 * 4);
    int*   res     = (int*)alloc(64);
    size_t zero_bytes = ofs;
    // rest (fully overwritten before use)
    int*   offsets = (int*)alloc((size_t)(N + 1) * 4);
    int*   cursor  = (int*)alloc((size_t)N * 4);
    int*   csr     = (int*)alloc((size_t)E * 4);
    float* nsrc    = (float*)alloc((size_t)N * 4);
    float* ndst    = (float*)alloc((size_t)N * 4);
    float* g       = (float*)alloc((size_t)N * C * 4);
    float* tn      = (float*)alloc((size_t)N * 4);
    unsigned int* U = (unsigned int*)alloc((size_t)N * 4);
    int*   sel     = (int*)alloc((size_t)N * 4);
    int*   pos     = (int*)alloc((size_t)N * 4);
    int*   bsums   = (int*)alloc(1024 * 4);
    int*   pbsums  = (int*)alloc(1024 * 4);

    hipMemsetAsync(d_ws, 0, zero_bytes, stream);

    int nb = (N + 1023) / 1024;
    k_detect<<<16, 256, 0, stream>>>(ei, E, res);
    k_deg<<<(E + 255) / 256, 256, 0, stream>>>(ei, E, res, outdeg, indeg);
    scan1<<<nb, 1024, 0, stream>>>(indeg, offsets, bsums, N, outdeg, nsrc, ndst);
    scan3b<<<nb, 1024, 0, stream>>>(offsets, bsums, cursor, N);
    k_csr<<<(E + 255) / 256, 256, 0, stream>>>(ei, E, res, cursor, csr);
    k_agg<<<(N + 3) / 4, 256, 0, stream>>>(x, csr, indeg, offsets, nsrc, ndst, g, N);
    k_gemm<<<(N + 191) / 192, 256, 0, stream>>>(g, W1, b1, W2, nsrc, tn, N);
    k_l2<<<(N + 255) / 256, 256, 0, stream>>>(csr, indeg, offsets, tn, ndst, b2, U, hist1, N);
    k_findbin1<<<1, 1024, 0, stream>>>(hist1, k, res);
    k_hist2<<<(N + 255) / 256, 256, 0, stream>>>(U, res, hist2, N);
    k_findbin2<<<1, 1024, 0, stream>>>(hist2, res);
    pscan1<<<nb, 1024, 0, stream>>>(U, res, pos, pbsums, N);   // pos holds packed prefix
    pscan2out<<<nb, 1024, 0, stream>>>(U, res, pos, pbsums, sel, pos, N);
    k_out<<<(N + 3) / 4, 256, 0, stream>>>(x, sel, pos, (float*)d_out, N);
}

// Round 11
// 468.764 us; speedup vs baseline: 1.0465x; 1.0465x over previous
//
#include <hip/hip_runtime.h>
#include <stdint.h>

constexpr int C = 128;
constexpr int F1 = 192;  // C + HID

// ---------------- shfl-based block primitives (1024 threads, 16 waves) ----------------
// Inclusive block scan: 2 barriers (vs 20 in the naive ladder).
__device__ __forceinline__ int block_scan_incl(int v, int* sh16) {
    int lane = threadIdx.x & 63;
    int wv   = threadIdx.x >> 6;
    int s = v;
    #pragma unroll
    for (int off = 1; off < 64; off <<= 1) {
        int t = __shfl_up(s, off);
        if (lane >= off) s += t;
    }
    if (lane == 63) sh16[wv] = s;
    __syncthreads();
    if (wv == 0) {
        int w = (lane < 16) ? sh16[lane] : 0;
        #pragma unroll
        for (int off = 1; off < 16; off <<= 1) {
            int t = __shfl_up(w, off);
            if (lane >= off) w += t;
        }
        if (lane < 16) sh16[lane] = w;
    }
    __syncthreads();
    return s + (wv ? sh16[wv - 1] : 0);
}

// Block-wide sum of v (all threads get result). 2 barriers.
__device__ __forceinline__ int block_reduce_add(int v, int* sh16) {
    #pragma unroll
    for (int off = 32; off > 0; off >>= 1) v += __shfl_xor(v, off);
    int lane = threadIdx.x & 63;
    int wv   = threadIdx.x >> 6;
    if (lane == 0) sh16[wv] = v;
    __syncthreads();
    int r = sh16[0];
    #pragma unroll
    for (int i = 1; i < 16; ++i) r += sh16[i];
    return r;
}

// ---------------- edge dtype detection ----------------
__global__ void k_detect(const int* __restrict__ ei, int E, int* __restrict__ res) {
    int t = blockIdx.x * 256 + threadIdx.x;
    int idx = 2 * t + 1;                 // odd word; t < 4096 <= E so in bounds
    if (idx < 2 * E && ei[idx] != 0) atomicOr(&res[5], 1);
}

// ---------------- degree ----------------
__global__ void k_deg(const int* __restrict__ ei, int E, const int* __restrict__ res,
                      int* __restrict__ outdeg, int* __restrict__ indeg) {
    int e = blockIdx.x * 256 + threadIdx.x;
    if (e < E) {
        bool i64 = (res[5] == 0);
        int s = i64 ? ei[2 * e]       : ei[e];
        int d = i64 ? ei[2 * (E + e)] : ei[E + e];
        atomicAdd(&outdeg[s], 1);
        atomicAdd(&indeg[d], 1);
    }
}

// ---------------- scan stage 1: block-local exclusive scan + block sums, fused norm ----------------
__global__ void scan1(const int* __restrict__ in, int* __restrict__ out,
                      int* __restrict__ bsums, int n,
                      const int* __restrict__ outdeg, float* __restrict__ nsrc,
                      float* __restrict__ ndst) {
    __shared__ int sh16[16];
    int i = blockIdx.x * 1024 + threadIdx.x;
    int v = (i < n) ? in[i] : 0;
    if (nsrc && i < n) {
        int od = outdeg[i]; if (od < 1) od = 1;
        int id = v;         if (id < 1) id = 1;
        nsrc[i] = (float)(1.0 / sqrt((double)od));
        ndst[i] = (float)(1.0 / sqrt((double)id));
    }
    int incl = block_scan_incl(v, sh16);
    if (i < n) out[i] = incl - v;                       // exclusive
    if (threadIdx.x == 1023) bsums[blockIdx.x] = incl;  // block total
}

// ---------------- scan stage 2: add prefix of bsums (reduced in-block), optional copy ----------------
__global__ void scan3b(int* __restrict__ data, const int* __restrict__ bsums,
                       int* __restrict__ copy2, int n) {
    __shared__ int sh16[16];
    int t = threadIdx.x;
    int v = (t < (int)blockIdx.x) ? bsums[t] : 0;   // gridDim <= 1024
    int boff = block_reduce_add(v, sh16);
    int i = blockIdx.x * 1024 + t;
    if (i < n) {
        int u = data[i] + boff;
        data[i] = u;
        if (copy2) copy2[i] = u;
    }
}

// ---------------- CSR build (by dst) ----------------
__global__ void k_csr(const int* __restrict__ ei, int E, const int* __restrict__ res,
                      int* __restrict__ cursor, int* __restrict__ csr) {
    int e = blockIdx.x * 256 + threadIdx.x;
    if (e < E) {
        bool i64 = (res[5] == 0);
        int s = i64 ? ei[2 * e]       : ei[e];
        int d = i64 ? ei[2 * (E + e)] : ei[E + e];
        int p = atomicAdd(&cursor[d], 1);
        csr[p] = s;
    }
}

// ---------------- layer-1 aggregation: one wave per node ----------------
// Sorted in-wave neighbor list (deterministic summation order across replays).
// Gather unroll-8: mean deg=8 -> one burst of 8 row loads in flight.
__global__ __launch_bounds__(256) void k_agg(const float* __restrict__ x,
        int* __restrict__ csr, const int* __restrict__ indeg,
        const int* __restrict__ offsets, const float* __restrict__ nsrc,
        const float* __restrict__ ndst, float* __restrict__ g, int N) {
    int wid  = (blockIdx.x * 256 + threadIdx.x) >> 6;  // node id (wave-uniform)
    int lane = threadIdx.x & 63;
    if (wid >= N) return;
    int deg = indeg[wid];
    int off = offsets[wid];
    float acc0 = 0.f, acc1 = 0.f;
    if (deg > 0 && deg <= 64) {
        int v = (lane < deg) ? csr[off + lane] : 0x7fffffff;
        int rank = 0;
        for (int j = 0; j < deg; ++j) {
            int vj = __builtin_amdgcn_readlane(v, j);
            rank += (vj < v) || (vj == v && j < lane);
        }
        int sv = __builtin_amdgcn_ds_permute(rank << 2, v);
        if (lane < deg) csr[off + lane] = sv;                // sorted write-back for k_l2
        float nsv = (lane < deg) ? nsrc[sv] : 0.f;
        int nsb = __float_as_int(nsv);
        int i = 0;
        for (; i + 7 < deg; i += 8) {
            float2 xr[8]; float nn[8];
            #pragma unroll
            for (int q = 0; q < 8; ++q) {
                int   sq = __builtin_amdgcn_readlane(sv, i + q);
                nn[q]    = __int_as_float(__builtin_amdgcn_readlane(nsb, i + q));
                xr[q] = ((const float2*)x)[(size_t)sq * 64 + lane];
            }
            #pragma unroll
            for (int q = 0; q < 8; ++q) {
                acc0 = fmaf(xr[q].x, nn[q], acc0);
                acc1 = fmaf(xr[q].y, nn[q], acc1);
            }
        }
        for (; i + 3 < deg; i += 4) {
            float2 xr[4]; float nn[4];
            #pragma unroll
            for (int q = 0; q < 4; ++q) {
                int   sq = __builtin_amdgcn_readlane(sv, i + q);
                nn[q]    = __int_as_float(__builtin_amdgcn_readlane(nsb, i + q));
                xr[q] = ((const float2*)x)[(size_t)sq * 64 + lane];
            }
            #pragma unroll
            for (int q = 0; q < 4; ++q) {
                acc0 = fmaf(xr[q].x, nn[q], acc0);
                acc1 = fmaf(xr[q].y, nn[q], acc1);
            }
        }
        for (; i < deg; ++i) {
            int   s0 = __builtin_amdgcn_readlane(sv, i);
            float n0 = __int_as_float(__builtin_amdgcn_readlane(nsb, i));
            float2 x0 = ((const float2*)x)[(size_t)s0 * 64 + lane];
            acc0 = fmaf(x0.x, n0, acc0); acc1 = fmaf(x0.y, n0, acc1);
        }
    } else if (deg > 64) {
        for (int i = 0; i < deg; ++i) {
            int s = csr[off + i];
            float ns = nsrc[s];
            float2 xr = ((const float2*)x)[(size_t)s * 64 + lane];
            acc0 = fmaf(xr.x, ns, acc0);
            acc1 = fmaf(xr.y, ns, acc1);
        }
    }
    float nd = ndst[wid];
    ((float2*)g)[(size_t)wid * 64 + lane] = make_float2(acc0 * nd, acc1 * nd);
}

// ---------------- fused GEMM + ReLU + dot(W2): register-blocked LDS GEMM ----------------
// ROUND-7 PROVEN STRUCTURE (83us, VALUBusy 47%). Round-8's 12x12 tile
// regressed (97us): 144 acc > VGPR budget -> AGPR shuttling. Keep 8x12.
__global__ __launch_bounds__(256, 3) void k_gemm(const float* __restrict__ g,
        const float* __restrict__ W1, const float* __restrict__ b1,
        const float* __restrict__ W2, const float* __restrict__ nsrc,
        float* __restrict__ tn, int N) {
    __shared__ float At[32 * 132];   // 16.9 KB
    __shared__ float Wt[32 * 200];   // 25.6 KB  -> 42.5 KB total, 3 blocks/CU
    int T  = threadIdx.x;
    int ng = T >> 4, jg = T & 15;
    int nb = blockIdx.x * 128;
    float acc[8][12];
    #pragma unroll
    for (int jj = 0; jj < 12; ++jj) {
        float b = b1[jg * 12 + jj];
        #pragma unroll
        for (int i = 0; i < 8; ++i) acc[i][jj] = b;
    }
    for (int s = 0; s < 4; ++s) {
        int k0 = s * 32;
        if (s) __syncthreads();          // previous step's reads done before overwrite
        // ---- stage A (transposed, pad-132) ----
        int kq = T & 7;
        #pragma unroll
        for (int t = 0; t < 4; ++t) {
            int nl = (T >> 3) + 32 * t;
            int node = nb + nl;
            float4 v = make_float4(0.f, 0.f, 0.f, 0.f);
            if (node < N) v = *(const float4*)(g + (size_t)node * 128 + k0 + kq * 4);
            int base = (kq * 4) * 132 + nl;
            At[base]       = v.x;
            At[base + 132] = v.y;
            At[base + 264] = v.z;
            At[base + 396] = v.w;
        }
        // ---- stage W (row-major, pad-200) ----
        #pragma unroll
        for (int i = 0; i < 6; ++i) {
            int idx = i * 256 + T;
            int r = idx / 48, j4 = idx - r * 48;
            float4 v = *(const float4*)(W1 + (k0 + r) * 192 + j4 * 4);
            *(float4*)&Wt[r * 200 + j4 * 4] = v;
        }
        __syncthreads();
        // ---- compute: 32 kk x (5 b128 reads, 96 fma) ----
        for (int kk = 0; kk < 32; ++kk) {
            float4 a0 = *(const float4*)&At[kk * 132 + ng * 8];
            float4 a1 = *(const float4*)&At[kk * 132 + ng * 8 + 4];
            float4 w0 = *(const float4*)&Wt[kk * 200 + jg * 12];
            float4 w1 = *(const float4*)&Wt[kk * 200 + jg * 12 + 4];
            float4 w2 = *(const float4*)&Wt[kk * 200 + jg * 12 + 8];
            float a[8]  = {a0.x, a0.y, a0.z, a0.w, a1.x, a1.y, a1.z, a1.w};
            float w[12] = {w0.x, w0.y, w0.z, w0.w, w1.x, w1.y, w1.z, w1.w,
                           w2.x, w2.y, w2.z, w2.w};
            #pragma unroll
            for (int i = 0; i < 8; ++i) {
                #pragma unroll
                for (int jj = 0; jj < 12; ++jj)
                    acc[i][jj] = fmaf(a[i], w[jj], acc[i][jj]);
            }
        }
    }
    // ---- epilogue: relu . W2, 16-lane butterfly per node, store tn ----
    float w2r[12];
    #pragma unroll
    for (int jj = 0; jj < 12; ++jj) w2r[jj] = W2[jg * 12 + jj];
    #pragma unroll
    for (int i = 0; i < 8; ++i) {
        float p = 0.f;
        #pragma unroll
        for (int jj = 0; jj < 12; ++jj) p = fmaf(fmaxf(acc[i][jj], 0.f), w2r[jj], p);
        p += __shfl_xor(p, 1);
        p += __shfl_xor(p, 2);
        p += __shfl_xor(p, 4);
        p += __shfl_xor(p, 8);
        if (jg == 0) {
            int node = nb + ng * 8 + i;
            if (node < N) tn[node] = p * nsrc[node];
        }
    }
}

// ---------------- layer-2 scalar aggregation + |score| bits + histogram ----------------
__global__ void k_l2(const int* __restrict__ csr, const int* __restrict__ indeg,
                     const int* __restrict__ offsets, const float* __restrict__ tn,
                     const float* __restrict__ ndst, const float* __restrict__ b2,
                     unsigned int* __restrict__ U, int* __restrict__ hist1, int N) {
    int n = blockIdx.x * 256 + threadIdx.x;
    if (n >= N) return;
    int deg = indeg[n], off = offsets[n];
    float s = 0.f;
    for (int i = 0; i < deg; ++i) s += tn[csr[off + i]];   // sorted order -> deterministic
    float sc = ndst[n] * s + b2[0];
    unsigned int u = __float_as_uint(fabsf(sc));
    U[n] = u;
    atomicAdd(&hist1[u >> 16], 1);
}

// ---------------- radix-select pass 1: high 16 bits ----------------
__global__ void k_findbin1(const int* __restrict__ hist, int k, int* __restrict__ res) {
    __shared__ int sh16[16];
    int t = threadIdx.x;
    int base = 65535 - 64 * t;      // chunk t covers 64 bins, high->low
    int s = 0;
    const int4* hv = (const int4*)(hist + base - 63);
    #pragma unroll
    for (int q = 0; q < 16; ++q) {
        int4 h4 = hv[q];
        s += h4.x + h4.y + h4.z + h4.w;
    }
    int incl = block_scan_incl(s, sh16);
    int before = incl - s;           // elements in all bins above this chunk
    if (before < k && incl >= k) {
        int cum = before;
        for (int q = 0; q < 64; ++q) {
            int b = base - q;
            int hh = hist[b];
            if (cum + hh >= k) { res[0] = b; res[1] = k - cum; break; }
            cum += hh;
        }
    }
}

__global__ void k_hist2(const unsigned int* __restrict__ U, const int* __restrict__ res,
                        int* __restrict__ hist2, int N) {
    int n = blockIdx.x * 256 + threadIdx.x;
    if (n < N) {
        unsigned int u = U[n];
        if ((int)(u >> 16) == res[0]) atomicAdd(&hist2[u & 0xffff], 1);
    }
}

// ---------------- radix-select pass 2: low 16 bits ----------------
__global__ void k_findbin2(const int* __restrict__ hist, int* __restrict__ res) {
    __shared__ int sh16[16];
    int k = res[1];
    int t = threadIdx.x;
    int base = 65535 - 64 * t;
    int s = 0;
    const int4* hv = (const int4*)(hist + base - 63);
    #pragma unroll
    for (int q = 0; q < 16; ++q) {
        int4 h4 = hv[q];
        s += h4.x + h4.y + h4.z + h4.w;
    }
    int incl = block_scan_incl(s, sh16);
    int before = incl - s;
    if (before < k && incl >= k) {
        int cum = before;
        for (int q = 0; q < 64; ++q) {
            int b = base - q;
            int hh = hist[b];
            if (cum + hh >= k) {
                res[2] = (int)(((unsigned int)res[0] << 16) | (unsigned int)b);  // threshold bits
                res[3] = k - cum;                                                // # ties to keep
                break;
            }
            cum += hh;
        }
    }
}

// ---------------- selection pair-scan stage 1: gt/eq packed block scan ----------------
// gt counts in low 16, eq in high 16 (block totals <= 1024 -> no carry).
__global__ void pscan1(const unsigned int* __restrict__ U, const int* __restrict__ res,
                       int* __restrict__ ppos, int* __restrict__ pbsums, int n) {
    __shared__ int sh16[16];
    unsigned int T = (unsigned int)res[2];
    int i = blockIdx.x * 1024 + threadIdx.x;
    int v = 0;
    if (i < n) {
        unsigned int u = U[i];
        v = (u > T) ? 1 : ((u == T) ? 0x10000 : 0);
    }
    int incl = block_scan_incl(v, sh16);
    if (i < n) ppos[i] = incl - v;   // exclusive packed prefix
    if (threadIdx.x == 1023) pbsums[blockIdx.x] = incl;
}

// ---------------- stage 2 fused with output copy ----------------
// sel = gt | (eq & eq_rank<need); pos = Pgt + min(Peq, need). Exactly
// reproduces jax top_k (|score|) + sort(idx). Then each wave copies its own
// 64 nodes' selected rows via ballot + readlane (no sel/pos round-trip).
__global__ void pscan2out(const unsigned int* __restrict__ U, const int* __restrict__ res,
                          const int* __restrict__ ppos, const int* __restrict__ pbsums,
                          const float* __restrict__ x, float* __restrict__ out, int n) {
    __shared__ int shg[16], she[16];
    int t = threadIdx.x;
    int b = (t < (int)blockIdx.x) ? pbsums[t] : 0;   // gridDim <= 1024
    int gsum = b & 0xffff, esum = b >> 16;
    // block-reduce both fields (2 barriers via two 16-slot combines)
    #pragma unroll
    for (int off = 32; off > 0; off >>= 1) {
        gsum += __shfl_xor(gsum, off);
        esum += __shfl_xor(esum, off);
    }
    int lane = t & 63, wv = t >> 6;
    if (lane == 0) { shg[wv] = gsum; she[wv] = esum; }
    __syncthreads();
    int Gp = 0, Ep = 0;
    #pragma unroll
    for (int i = 0; i < 16; ++i) { Gp += shg[i]; Ep += she[i]; }
    int i = blockIdx.x * 1024 + t;
    int selbit = 0, posv = 0;
    if (i < n) {
        unsigned int T = (unsigned int)res[2];
        int need = res[3];
        unsigned int u = U[i];
        int p = ppos[i];
        int Pgt = (p & 0xffff) + Gp;
        int Peq = (p >> 16) + Ep;
        int gt = (u > T), eq = (u == T);
        selbit = gt | (eq & (Peq < need ? 1 : 0));
        posv = Pgt + (Peq < need ? Peq : need);
    }
    // wave-cooperative row copy of selected nodes
    unsigned long long m = __ballot(selbit);
    int nbase = blockIdx.x * 1024 + wv * 64;
    while (m) {
        int bit = __ffsll((long long)m) - 1;
        m &= m - 1;
        int p = __builtin_amdgcn_readlane(posv, bit);
        int node = nbase + bit;
        ((float2*)out)[(size_t)p * 64 + lane] = ((const float2*)x)[(size_t)node * 64 + lane];
    }
}

extern "C" void kernel_launch(void* const* d_in, const int* in_sizes, int n_in,
                              void* d_out, int out_size, void* d_ws, size_t ws_size,
                              hipStream_t stream) {
    const float* x  = (const float*)d_in[0];
    const int*   ei = (const int*)d_in[1];
    const float* W1 = (const float*)d_in[2];
    const float* b1 = (const float*)d_in[3];
    const float* W2 = (const float*)d_in[4];
    const float* b2 = (const float*)d_in[5];
    int N = in_sizes[0] / C;            // 100000
    int E = in_sizes[1] / 2;            // 800000
    int k = out_size / C;               // harness-derived k

    char* w = (char*)d_ws;
    size_t ofs = 0;
    auto alloc = [&](size_t bytes) -> char* {
        char* p = w + ofs;
        ofs += (bytes + 511) & ~(size_t)511;
        return p;
    };
    // zero-init region first (single contiguous memset)
    int*   outdeg  = (int*)alloc((size_t)N * 4);
    int*   indeg   = (int*)alloc((size_t)N * 4);
    int*   hist1   = (int*)alloc(65536 * 4);
    int*   hist2   = (int*)alloc(65536 * 4);
    int*   res     = (int*)alloc(64);
    size_t zero_bytes = ofs;
    // rest (fully overwritten before use)
    int*   offsets = (int*)alloc((size_t)(N + 1) * 4);
    int*   cursor  = (int*)alloc((size_t)N * 4);
    int*   csr     = (int*)alloc((size_t)E * 4);
    float* nsrc    = (float*)alloc((size_t)N * 4);
    float* ndst    = (float*)alloc((size_t)N * 4);
    float* g       = (float*)alloc((size_t)N * C * 4);
    float* tn      = (float*)alloc((size_t)N * 4);
    unsigned int* U = (unsigned int*)alloc((size_t)N * 4);
    int*   ppos    = (int*)alloc((size_t)N * 4);
    int*   bsums   = (int*)alloc(1024 * 4);
    int*   pbsums  = (int*)alloc(1024 * 4);

    hipMemsetAsync(d_ws, 0, zero_bytes, stream);

    int nb = (N + 1023) / 1024;
    k_detect<<<16, 256, 0, stream>>>(ei, E, res);
    k_deg<<<(E + 255) / 256, 256, 0, stream>>>(ei, E, res, outdeg, indeg);
    scan1<<<nb, 1024, 0, stream>>>(indeg, offsets, bsums, N, outdeg, nsrc, ndst);
    scan3b<<<nb, 1024, 0, stream>>>(offsets, bsums, cursor, N);
    k_csr<<<(E + 255) / 256, 256, 0, stream>>>(ei, E, res, cursor, csr);
    k_agg<<<(N + 3) / 4, 256, 0, stream>>>(x, csr, indeg, offsets, nsrc, ndst, g, N);
    k_gemm<<<(N + 127) / 128, 256, 0, stream>>>(g, W1, b1, W2, nsrc, tn, N);
    k_l2<<<(N + 255) / 256, 256, 0, stream>>>(csr, indeg, offsets, tn, ndst, b2, U, hist1, N);
    k_findbin1<<<1, 1024, 0, stream>>>(hist1, k, res);
    k_hist2<<<(N + 255) / 256, 256, 0, stream>>>(U, res, hist2, N);
    k_findbin2<<<1, 1024, 0, stream>>>(hist2, res);
    pscan1<<<nb, 1024, 0, stream>>>(U, res, ppos, pbsums, N);
    pscan2out<<<nb, 1024, 0, stream>>>(U, res, ppos, pbsums, x, (float*)d_out, N);
}